// Round 7
// baseline (239.787 us; speedup 1.0000x reference)
//
#include <hip/hip_runtime.h>
#include <hip/hip_bf16.h>

// RandScatter with a CONSTANT score matrix:
//   route = argmax(score, axis=1) = [0, 1, 1, 1]
//   out = concat(inputs[[0]], inputs[[1,2,3]]) = inputs, verbatim.
// Pure 128 MiB fp32 D2D copy, memory-bound.
//
// Round 2: hipMemcpyAsync under capture -> SDMA path, 222 us total.
// Round 6: naive grid-stride float4 copy -> VGPR=8, ONE load in flight per
//   wave -> latency-bound, 81 us dispatch @ 2.5 TB/s.
// Round 7: manual x8 unroll -> 8 independent global_load_dwordx4 in flight
//   per wave (8 KB MLP/wave), lane-contiguous per instruction. Target the
//   ~6.3 TB/s kernel-copy ceiling (~43 us for 268 MB).

__global__ __launch_bounds__(256) void copy_f4x8_kernel(
    const float4* __restrict__ src, float4* __restrict__ dst, long n4) {
    long nt  = (long)gridDim.x * blockDim.x;   // total threads
    long i   = (long)blockIdx.x * blockDim.x + threadIdx.x;
    // Main loop: 8 float4s (128 B) per thread-iteration, stride nt between
    // the unrolled accesses so each load instruction is fully coalesced.
    for (; i + 7 * nt < n4; i += 8 * nt) {
        float4 a0 = src[i];
        float4 a1 = src[i + nt];
        float4 a2 = src[i + 2 * nt];
        float4 a3 = src[i + 3 * nt];
        float4 a4 = src[i + 4 * nt];
        float4 a5 = src[i + 5 * nt];
        float4 a6 = src[i + 6 * nt];
        float4 a7 = src[i + 7 * nt];
        dst[i]          = a0;
        dst[i + nt]     = a1;
        dst[i + 2 * nt] = a2;
        dst[i + 3 * nt] = a3;
        dst[i + 4 * nt] = a4;
        dst[i + 5 * nt] = a5;
        dst[i + 6 * nt] = a6;
        dst[i + 7 * nt] = a7;
    }
    // Tail (empty for this problem: n4 = 8388608 = 16 * 524288 threads).
    for (; i < n4; i += nt) dst[i] = src[i];
}

extern "C" void kernel_launch(void* const* d_in, const int* in_sizes, int n_in,
                              void* d_out, int out_size, void* d_ws, size_t ws_size,
                              hipStream_t stream) {
    (void)n_in; (void)d_ws; (void)ws_size; (void)in_sizes;
    const float4* in = (const float4*)d_in[0];
    float4* out = (float4*)d_out;
    long n4 = (long)out_size / 4;   // 8388608 float4s
    const int block = 256;
    const int grid = 2048;          // 524288 threads -> exactly 16 float4s each
    copy_f4x8_kernel<<<grid, block, 0, stream>>>(in, out, n4);
}

// Round 8
// 218.138 us; speedup vs baseline: 1.0992x; 1.0992x over previous
//
#include <hip/hip_runtime.h>
#include <hip/hip_bf16.h>

// RandScatter with a CONSTANT score matrix:
//   route = argmax(score, axis=1) = [0, 1, 1, 1]
//   out = concat(inputs[[0]], inputs[[1,2,3]]) = inputs, verbatim.
// Pure 128 MiB fp32 D2D copy, memory-bound.
//
// History:
//  R2: hipMemcpyAsync under capture -> SDMA path (slow).
//  R6: naive float4 grid-stride: 81 us @ ~3 TB/s effective.
//  R7: x8 unroll (8 loads in flight): 90 us — MLP was NOT the limiter.
//  R8 theory: streaming read+write churns L2/L3 allocation (128 MiB of
//    write-allocates through a 32 MiB L2). Use nontemporal load/store
//    (nt bit: no cache allocation, write-through) on native 16B vectors.

typedef float f4 __attribute__((ext_vector_type(4)));

__global__ __launch_bounds__(256) void copy_nt_kernel(
    const f4* __restrict__ src, f4* __restrict__ dst, int n4) {
    int stride = (int)(gridDim.x * blockDim.x);
    for (int i = (int)(blockIdx.x * blockDim.x + threadIdx.x); i < n4; i += stride) {
        f4 v = __builtin_nontemporal_load(src + i);
        __builtin_nontemporal_store(v, dst + i);
    }
}

extern "C" void kernel_launch(void* const* d_in, const int* in_sizes, int n_in,
                              void* d_out, int out_size, void* d_ws, size_t ws_size,
                              hipStream_t stream) {
    (void)n_in; (void)d_ws; (void)ws_size; (void)in_sizes;
    const f4* in = (const f4*)d_in[0];
    f4* out = (f4*)d_out;
    int n4 = out_size / 4;          // 8388608 float4s (fits int32)
    const int block = 256;
    const int grid = 4096;          // 1M threads, 8 float4s each
    copy_nt_kernel<<<grid, block, 0, stream>>>(in, out, n4);
}